// Round 2
// baseline (856.821 us; speedup 1.0000x reference)
//
#include <hip/hip_runtime.h>

#define NN 50000
#define NE 800000
#define DIM 128
#define NLAYERS 3

// ---------------- CSR build ----------------
__global__ void hist_kernel(const int* __restrict__ tgt, int* __restrict__ counts, int E) {
    int e = blockIdx.x * blockDim.x + threadIdx.x;
    if (e < E) atomicAdd(&counts[tgt[e]], 1);
}

// 1024 threads = 16 waves. Wave-shuffle inclusive scan (no barriers inside),
// then serial scan of the 16 wave sums. 3 barriers per 1024-chunk.
__global__ __launch_bounds__(1024) void scan_kernel(const int* __restrict__ counts,
                                                    int* __restrict__ offsets,
                                                    int* __restrict__ cursor, int n) {
    __shared__ int wsum[16];
    __shared__ int stot;
    int tid = threadIdx.x;
    int lane = tid & 63, wid = tid >> 6;
    int base = 0;
    for (int start = 0; start < n; start += 1024) {
        int i = start + tid;
        int v = (i < n) ? counts[i] : 0;
        int incl = v;
#pragma unroll
        for (int off = 1; off < 64; off <<= 1) {
            int t = __shfl_up(incl, off);
            if (lane >= off) incl += t;
        }
        if (lane == 63) wsum[wid] = incl;
        __syncthreads();
        if (tid == 0) {
            int s = 0;
#pragma unroll
            for (int w = 0; w < 16; w++) { int t = wsum[w]; wsum[w] = s; s += t; }
            stot = s;
        }
        __syncthreads();
        int excl = base + wsum[wid] + incl - v;
        if (i < n) { offsets[i] = excl; cursor[i] = excl; }
        base += stot;
        __syncthreads();  // protect wsum/stot from next iteration's writes
    }
    if (tid == 0) offsets[n] = base;
}

__global__ void scatter_kernel(const int* __restrict__ src, const int* __restrict__ tgt,
                               const float* __restrict__ ea,
                               int* __restrict__ cursor, int2* __restrict__ sedge, int E) {
    int e = blockIdx.x * blockDim.x + threadIdx.x;
    if (e >= E) return;
    int t = tgt[e];
    int pos = atomicAdd(&cursor[t], 1);
    sedge[pos] = make_int2(src[e], __float_as_int(ea[e]));
}

// ---------------- per-layer aggregation ----------------
// one wave per node; lane owns dims (2*lane, 2*lane+1)
__global__ __launch_bounds__(128) void agg_kernel(
    const float* __restrict__ hprev, const int* __restrict__ offs,
    const int2* __restrict__ sedge,
    const float* __restrict__ lw, const float* __restrict__ lb,
    const float* __restrict__ epsp, int layer,
    float* __restrict__ outb, int N) {
    int wv = threadIdx.x >> 6;
    int node = blockIdx.x * 2 + wv;
    if (node >= N) return;
    int lane = threadIdx.x & 63;
    int d0 = lane * 2;
    float2 lwv = *(const float2*)(lw + d0);
    float2 lbv = *(const float2*)(lb + d0);
    int s0 = offs[node], s1 = offs[node + 1];
    float a0 = 0.f, a1 = 0.f;
    int2 p = sedge[s0];
    for (int i = s0; i < s1; ++i) {
        int2 pn = (i + 1 < s1) ? sedge[i + 1] : p;
        int s = p.x;
        float w = __int_as_float(p.y);
        float2 h = *(const float2*)(hprev + (size_t)s * DIM + d0);
        a0 += fmaxf(h.x + w * lwv.x + lbv.x, 0.f);
        a1 += fmaxf(h.y + w * lwv.y + lbv.y, 0.f);
        p = pn;
    }
    float inv = 1.f / (float)(s1 - s0);
    float ge = 1.f + epsp[layer];
    float2 hs = *(const float2*)(hprev + (size_t)node * DIM + d0);
    float2 o;
    o.x = a0 * inv + ge * hs.x;
    o.y = a1 * inv + ge * hs.y;
    *(float2*)(outb + (size_t)node * DIM + d0) = o;
}

// ---------------- per-layer 2-layer MLP ----------------
// 32 nodes per 256-thread block; LDS tiles transposed [k][node], row stride 36
// (144 B: 16B-aligned rows for b128 broadcast reads)
#define MLP_NT 32
#define MLP_STR 36
__global__ __launch_bounds__(256) void mlp_kernel(
    const float* __restrict__ in, const float* __restrict__ w1,
    const float* __restrict__ b1, const float* __restrict__ w2,
    const float* __restrict__ b2, float* __restrict__ out, int N) {
    __shared__ float s_a[DIM * MLP_STR];
    __shared__ float s_t[DIM * MLP_STR];
    int tid = threadIdx.x;
    int n0 = blockIdx.x * MLP_NT;
    for (int idx = tid; idx < MLP_NT * DIM; idx += 256) {
        int node = idx >> 7, k = idx & 127;
        float v = (n0 + node < N) ? in[(size_t)(n0 + node) * DIM + k] : 0.f;
        s_a[k * MLP_STR + node] = v;
    }
    __syncthreads();
    int j = tid & 127, g = tid >> 7;
    float acc[16];
#pragma unroll
    for (int m = 0; m < 16; m++) acc[m] = 0.f;
    for (int k = 0; k < DIM; k++) {
        float w = w1[k * DIM + j];
        const float* row = &s_a[k * MLP_STR + g * 16];
#pragma unroll
        for (int m = 0; m < 16; m++) acc[m] = fmaf(row[m], w, acc[m]);
    }
    float bv1 = b1[j];
#pragma unroll
    for (int m = 0; m < 16; m++)
        s_t[j * MLP_STR + g * 16 + m] = fmaxf(acc[m] + bv1, 0.f);
    __syncthreads();
#pragma unroll
    for (int m = 0; m < 16; m++) acc[m] = 0.f;
    for (int k = 0; k < DIM; k++) {
        float w = w2[k * DIM + j];
        const float* row = &s_t[k * MLP_STR + g * 16];
#pragma unroll
        for (int m = 0; m < 16; m++) acc[m] = fmaf(row[m], w, acc[m]);
    }
    float bv2 = b2[j];
#pragma unroll
    for (int m = 0; m < 16; m++) {
        int node = n0 + g * 16 + m;
        if (node < N) out[(size_t)node * DIM + j] = acc[m] + bv2;
    }
}

// ---------------- final projection  cat[x,h1,h2,h3] @ final_w + final_b ----------------
#define FIN_NT 16
#define FIN_STR 20
__global__ __launch_bounds__(256) void final_kernel(
    const float* __restrict__ x, const float* __restrict__ h1,
    const float* __restrict__ h2, const float* __restrict__ h3,
    const float* __restrict__ fw, const float* __restrict__ fb,
    float* __restrict__ out, int N) {
    __shared__ float s_a[4 * DIM * FIN_STR];
    int tid = threadIdx.x;
    int n0 = blockIdx.x * FIN_NT;
    for (int idx = tid; idx < FIN_NT * DIM; idx += 256) {
        int node = idx >> 7, k = idx & 127;
        bool ok = (n0 + node) < N;
        size_t off = (size_t)(n0 + node) * DIM + k;
        s_a[k * FIN_STR + node] = ok ? x[off] : 0.f;
        s_a[(DIM + k) * FIN_STR + node] = ok ? h1[off] : 0.f;
        s_a[(2 * DIM + k) * FIN_STR + node] = ok ? h2[off] : 0.f;
        s_a[(3 * DIM + k) * FIN_STR + node] = ok ? h3[off] : 0.f;
    }
    __syncthreads();
    int j = tid & 127, g = tid >> 7;
    float acc[8];
#pragma unroll
    for (int m = 0; m < 8; m++) acc[m] = 0.f;
    for (int k = 0; k < 4 * DIM; k++) {
        float w = fw[k * DIM + j];
        const float* row = &s_a[k * FIN_STR + g * 8];
#pragma unroll
        for (int m = 0; m < 8; m++) acc[m] = fmaf(row[m], w, acc[m]);
    }
    float bv = fb[j];
#pragma unroll
    for (int m = 0; m < 8; m++) {
        int node = n0 + g * 8 + m;
        if (node < N) out[(size_t)node * DIM + j] = acc[m] + bv;
    }
}

extern "C" void kernel_launch(void* const* d_in, const int* in_sizes, int n_in,
                              void* d_out, int out_size, void* d_ws, size_t ws_size,
                              hipStream_t stream) {
    const float* x   = (const float*)d_in[0];
    const int* edge_index = (const int*)d_in[1];
    const float* ea  = (const float*)d_in[2];
    const float* lw  = (const float*)d_in[3];
    const float* lb  = (const float*)d_in[4];
    const float* eps = (const float*)d_in[5];
    const float* w1  = (const float*)d_in[6];
    const float* b1  = (const float*)d_in[7];
    const float* w2  = (const float*)d_in[8];
    const float* b2  = (const float*)d_in[9];
    const float* fw  = (const float*)d_in[10];
    const float* fb  = (const float*)d_in[11];
    float* out = (float*)d_out;

    const int N = NN, E = NE;
    const int* src = edge_index;
    const int* tgt = edge_index + E;

    char* ws = (char*)d_ws;
    size_t off = 0;
    auto alloc = [&](size_t bytes) {
        void* p = ws + off;
        off += (bytes + 255) & ~(size_t)255;
        return p;
    };
    int*   counts  = (int*)alloc((size_t)N * 4);
    int*   offsets = (int*)alloc((size_t)(N + 1) * 4);
    int*   cursor  = (int*)alloc((size_t)N * 4);
    int2*  sedge   = (int2*)alloc((size_t)E * 8);
    float* hbuf[3];
    for (int i = 0; i < 3; i++) hbuf[i] = (float*)alloc((size_t)N * DIM * 4);
    float* outb = (float*)alloc((size_t)N * DIM * 4);
    (void)ws_size; (void)in_sizes; (void)n_in; (void)out_size;

    hipMemsetAsync(counts, 0, (size_t)N * 4, stream);
    hist_kernel<<<(E + 255) / 256, 256, 0, stream>>>(tgt, counts, E);
    scan_kernel<<<1, 1024, 0, stream>>>(counts, offsets, cursor, N);
    scatter_kernel<<<(E + 255) / 256, 256, 0, stream>>>(src, tgt, ea, cursor, sedge, E);

    for (int l = 0; l < NLAYERS; l++) {
        const float* hin = (l == 0) ? x : hbuf[l - 1];
        agg_kernel<<<(N + 1) / 2, 128, 0, stream>>>(hin, offsets, sedge,
            lw + l * DIM, lb + l * DIM, eps, l, outb, N);
        mlp_kernel<<<(N + MLP_NT - 1) / MLP_NT, 256, 0, stream>>>(
            outb, w1 + (size_t)l * DIM * DIM, b1 + l * DIM,
            w2 + (size_t)l * DIM * DIM, b2 + l * DIM, hbuf[l], N);
    }
    final_kernel<<<(N + FIN_NT - 1) / FIN_NT, 256, 0, stream>>>(
        x, hbuf[0], hbuf[1], hbuf[2], fw, fb, out, N);
}

// Round 3
// 673.663 us; speedup vs baseline: 1.2719x; 1.2719x over previous
//
#include <hip/hip_runtime.h>

#define NN 50000
#define NE 800000
#define DIM 128
#define NLAYERS 3

// ---------------- CSR build ----------------
__global__ void hist_kernel(const int* __restrict__ tgt, int* __restrict__ counts, int E) {
    int e = blockIdx.x * blockDim.x + threadIdx.x;
    if (e < E) atomicAdd(&counts[tgt[e]], 1);
}

// per-1024-chunk partial sums
__global__ __launch_bounds__(256) void scan_partial_kernel(const int* __restrict__ counts,
                                                           int* __restrict__ psum, int n) {
    __shared__ int ws[4];
    int b = blockIdx.x, t = threadIdx.x;
    int idx = b * 1024 + t * 4;
    int v = 0;
    if (idx < n) {
        int4 c = *(const int4*)(counts + idx);
        v = c.x + c.y + c.z + c.w;
    }
#pragma unroll
    for (int o = 32; o > 0; o >>= 1) v += __shfl_xor(v, o);
    int lane = t & 63, wid = t >> 6;
    if (lane == 0) ws[wid] = v;
    __syncthreads();
    if (t == 0) psum[b] = ws[0] + ws[1] + ws[2] + ws[3];
}

// scan the (<=64) partials in one wave; also writes offsets[n] = total
__global__ __launch_bounds__(64) void scan_small_kernel(const int* __restrict__ psum,
                                                        int* __restrict__ pbase,
                                                        int* __restrict__ offsets,
                                                        int nb, int n) {
    int lane = threadIdx.x;
    int v = (lane < nb) ? psum[lane] : 0;
    int incl = v;
#pragma unroll
    for (int o = 1; o < 64; o <<= 1) {
        int t = __shfl_up(incl, o);
        if (lane >= o) incl += t;
    }
    if (lane < nb) pbase[lane] = incl - v;
    if (lane == 63) offsets[n] = incl;
}

__global__ __launch_bounds__(256) void scan_apply_kernel(const int* __restrict__ counts,
                                                         const int* __restrict__ pbase,
                                                         int* __restrict__ offsets,
                                                         int* __restrict__ cursor, int n) {
    __shared__ int ws[4];
    int b = blockIdx.x, t = threadIdx.x;
    int lane = t & 63, wid = t >> 6;
    int idx = b * 1024 + t * 4;
    int4 c = make_int4(0, 0, 0, 0);
    if (idx < n) c = *(const int4*)(counts + idx);
    int tsum = c.x + c.y + c.z + c.w;
    int incl = tsum;
#pragma unroll
    for (int o = 1; o < 64; o <<= 1) {
        int tt = __shfl_up(incl, o);
        if (lane >= o) incl += tt;
    }
    if (lane == 63) ws[wid] = incl;
    __syncthreads();
    int wbase = pbase[b];
    for (int w = 0; w < wid; w++) wbase += ws[w];
    if (idx < n) {
        int e0 = wbase + incl - tsum;
        int4 o;
        o.x = e0;
        o.y = e0 + c.x;
        o.z = o.y + c.y;
        o.w = o.z + c.z;
        *(int4*)(offsets + idx) = o;
        *(int4*)(cursor + idx) = o;
    }
}

__global__ void scatter_kernel(const int* __restrict__ src, const int* __restrict__ tgt,
                               const float* __restrict__ ea,
                               int* __restrict__ cursor, int2* __restrict__ sedge, int E) {
    int e = blockIdx.x * blockDim.x + threadIdx.x;
    if (e >= E) return;
    int t = tgt[e];
    int pos = atomicAdd(&cursor[t], 1);
    sedge[pos] = make_int2(src[e], __float_as_int(ea[e]));
}

// ---------------- per-layer aggregation ----------------
// one wave per node; lane owns dims (2*lane, 2*lane+1); 2-wide pipelined gather
__global__ __launch_bounds__(128) void agg_kernel(
    const float* __restrict__ hprev, const int* __restrict__ offs,
    const int2* __restrict__ sedge,
    const float* __restrict__ lw, const float* __restrict__ lb,
    const float* __restrict__ epsp, int layer,
    float* __restrict__ outb, int N) {
    int wv = threadIdx.x >> 6;
    int node = blockIdx.x * 2 + wv;
    if (node >= N) return;
    int lane = threadIdx.x & 63;
    int d0 = lane * 2;
    float2 lwv = *(const float2*)(lw + d0);
    float2 lbv = *(const float2*)(lb + d0);
    int s0 = offs[node], s1 = offs[node + 1];
    int cnt = s1 - s0;
    float a0 = 0.f, a1 = 0.f;

    int2 pa = sedge[s0];
    int2 pb = (cnt > 1) ? sedge[s0 + 1] : pa;
    float2 ha = *(const float2*)(hprev + (size_t)pa.x * DIM + d0);
    float2 hb = *(const float2*)(hprev + (size_t)pb.x * DIM + d0);
    int i = s0;
    for (; i + 2 < s1; i += 2) {
        int2 na = sedge[i + 2];
        int2 nb = (i + 3 < s1) ? sedge[i + 3] : na;
        float2 hna = *(const float2*)(hprev + (size_t)na.x * DIM + d0);
        float2 hnb = *(const float2*)(hprev + (size_t)nb.x * DIM + d0);
        float wa = __int_as_float(pa.y), wb = __int_as_float(pb.y);
        a0 += fmaxf(ha.x + wa * lwv.x + lbv.x, 0.f);
        a1 += fmaxf(ha.y + wa * lwv.y + lbv.y, 0.f);
        a0 += fmaxf(hb.x + wb * lwv.x + lbv.x, 0.f);
        a1 += fmaxf(hb.y + wb * lwv.y + lbv.y, 0.f);
        pa = na; pb = nb; ha = hna; hb = hnb;
    }
    {
        float wa = __int_as_float(pa.y);
        a0 += fmaxf(ha.x + wa * lwv.x + lbv.x, 0.f);
        a1 += fmaxf(ha.y + wa * lwv.y + lbv.y, 0.f);
        if (i + 1 < s1) {
            float wb = __int_as_float(pb.y);
            a0 += fmaxf(hb.x + wb * lwv.x + lbv.x, 0.f);
            a1 += fmaxf(hb.y + wb * lwv.y + lbv.y, 0.f);
        }
    }
    float inv = 1.f / (float)cnt;
    float ge = 1.f + epsp[layer];
    float2 hs = *(const float2*)(hprev + (size_t)node * DIM + d0);
    float2 o;
    o.x = a0 * inv + ge * hs.x;
    o.y = a1 * inv + ge * hs.y;
    *(float2*)(outb + (size_t)node * DIM + d0) = o;
}

// ---------------- generic register-tiled GEMM ----------------
// out[n][j] = (relu?) sum_k A[n][k] * W[k][j] + bias[j]
// A given as NSRC row-major [N][128] sources concatenated along k.
// Block: 256 threads, tile 128 nodes x 128 cols, thread = 8 nodes x 8 cols.
// KT=32 k-chunks staged in LDS (A transposed, W direct). In-place safe per
// block (reads only own rows; epilogue writes after all staging reads).
#define GT_KT 32
#define SA_STR 132
template <int NSRC, bool RELU>
__global__ __launch_bounds__(256) void gemm_kernel(
    const float* __restrict__ a0, const float* __restrict__ a1,
    const float* __restrict__ a2, const float* __restrict__ a3,
    const float* __restrict__ w, const float* __restrict__ bias,
    float* __restrict__ out, int N) {
    __shared__ float s_a[GT_KT][SA_STR];
    __shared__ float s_w[GT_KT][128];
    const float* srcs[4] = {a0, a1, a2, a3};
    int tid = threadIdx.x;
    int n0 = blockIdx.x * 128;
    int cg = tid & 15;   // col group: cols cg*8..cg*8+7
    int ng = tid >> 4;   // node group: nodes ng*8..ng*8+7
    float acc[8][8];
#pragma unroll
    for (int m = 0; m < 8; m++)
#pragma unroll
        for (int c = 0; c < 8; c++) acc[m][c] = 0.f;

    const int K = NSRC * 128;
    for (int k0 = 0; k0 < K; k0 += GT_KT) {
        const float* asrc = srcs[k0 >> 7];
        int kl = k0 & 127;
#pragma unroll
        for (int pass = 0; pass < 4; ++pass) {
            int node = (tid >> 3) + 32 * pass;
            int kq = (tid & 7) * 4;
            float4 v = make_float4(0.f, 0.f, 0.f, 0.f);
            if (n0 + node < N)
                v = *(const float4*)(asrc + (size_t)(n0 + node) * 128 + kl + kq);
            s_a[kq + 0][node] = v.x;
            s_a[kq + 1][node] = v.y;
            s_a[kq + 2][node] = v.z;
            s_a[kq + 3][node] = v.w;
        }
        {
            float4* dst = (float4*)&s_w[0][0];
            const float4* srcp = (const float4*)(w + (size_t)k0 * 128);
#pragma unroll
            for (int i = 0; i < 4; ++i) dst[tid + 256 * i] = srcp[tid + 256 * i];
        }
        __syncthreads();
#pragma unroll 8
        for (int k = 0; k < GT_KT; ++k) {
            float af[8], wf[8];
            *(float4*)&af[0] = *(const float4*)&s_a[k][ng * 8];
            *(float4*)&af[4] = *(const float4*)&s_a[k][ng * 8 + 4];
            *(float4*)&wf[0] = *(const float4*)&s_w[k][cg * 8];
            *(float4*)&wf[4] = *(const float4*)&s_w[k][cg * 8 + 4];
#pragma unroll
            for (int m = 0; m < 8; m++)
#pragma unroll
                for (int c = 0; c < 8; c++)
                    acc[m][c] = fmaf(af[m], wf[c], acc[m][c]);
        }
        __syncthreads();
    }
    float4 bv0 = *(const float4*)(bias + cg * 8);
    float4 bv1 = *(const float4*)(bias + cg * 8 + 4);
#pragma unroll
    for (int m = 0; m < 8; m++) {
        int node = n0 + ng * 8 + m;
        if (node < N) {
            float4 o0, o1;
            o0.x = acc[m][0] + bv0.x; o0.y = acc[m][1] + bv0.y;
            o0.z = acc[m][2] + bv0.z; o0.w = acc[m][3] + bv0.w;
            o1.x = acc[m][4] + bv1.x; o1.y = acc[m][5] + bv1.y;
            o1.z = acc[m][6] + bv1.z; o1.w = acc[m][7] + bv1.w;
            if (RELU) {
                o0.x = fmaxf(o0.x, 0.f); o0.y = fmaxf(o0.y, 0.f);
                o0.z = fmaxf(o0.z, 0.f); o0.w = fmaxf(o0.w, 0.f);
                o1.x = fmaxf(o1.x, 0.f); o1.y = fmaxf(o1.y, 0.f);
                o1.z = fmaxf(o1.z, 0.f); o1.w = fmaxf(o1.w, 0.f);
            }
            float* op = out + (size_t)node * 128 + cg * 8;
            *(float4*)op = o0;
            *(float4*)(op + 4) = o1;
        }
    }
}

extern "C" void kernel_launch(void* const* d_in, const int* in_sizes, int n_in,
                              void* d_out, int out_size, void* d_ws, size_t ws_size,
                              hipStream_t stream) {
    const float* x   = (const float*)d_in[0];
    const int* edge_index = (const int*)d_in[1];
    const float* ea  = (const float*)d_in[2];
    const float* lw  = (const float*)d_in[3];
    const float* lb  = (const float*)d_in[4];
    const float* eps = (const float*)d_in[5];
    const float* w1  = (const float*)d_in[6];
    const float* b1  = (const float*)d_in[7];
    const float* w2  = (const float*)d_in[8];
    const float* b2  = (const float*)d_in[9];
    const float* fw  = (const float*)d_in[10];
    const float* fb  = (const float*)d_in[11];
    float* out = (float*)d_out;

    const int N = NN, E = NE;
    const int* src = edge_index;
    const int* tgt = edge_index + E;
    const int NB = (N + 1023) / 1024;  // 49

    char* ws = (char*)d_ws;
    size_t off = 0;
    auto alloc = [&](size_t bytes) {
        void* p = ws + off;
        off += (bytes + 255) & ~(size_t)255;
        return p;
    };
    int*   counts  = (int*)alloc((size_t)N * 4);
    int*   offsets = (int*)alloc((size_t)(N + 1) * 4);
    int*   cursor  = (int*)alloc((size_t)N * 4);
    int*   psum    = (int*)alloc((size_t)NB * 4);
    int*   pbase   = (int*)alloc((size_t)NB * 4);
    int2*  sedge   = (int2*)alloc((size_t)E * 8);
    float* hbuf[3];
    for (int i = 0; i < 3; i++) hbuf[i] = (float*)alloc((size_t)N * DIM * 4);
    float* outb = (float*)alloc((size_t)N * DIM * 4);
    (void)ws_size; (void)in_sizes; (void)n_in; (void)out_size;

    hipMemsetAsync(counts, 0, (size_t)N * 4, stream);
    hist_kernel<<<(E + 255) / 256, 256, 0, stream>>>(tgt, counts, E);
    scan_partial_kernel<<<NB, 256, 0, stream>>>(counts, psum, N);
    scan_small_kernel<<<1, 64, 0, stream>>>(psum, pbase, offsets, NB, N);
    scan_apply_kernel<<<NB, 256, 0, stream>>>(counts, pbase, offsets, cursor, N);
    scatter_kernel<<<(E + 255) / 256, 256, 0, stream>>>(src, tgt, ea, cursor, sedge, E);

    const int GB = (N + 127) / 128;  // 391
    for (int l = 0; l < NLAYERS; l++) {
        const float* hin = (l == 0) ? x : hbuf[l - 1];
        agg_kernel<<<(N + 1) / 2, 128, 0, stream>>>(hin, offsets, sedge,
            lw + l * DIM, lb + l * DIM, eps, l, outb, N);
        // hidden = relu(outb @ w1 + b1), in-place
        gemm_kernel<1, true><<<GB, 256, 0, stream>>>(
            outb, nullptr, nullptr, nullptr,
            w1 + (size_t)l * DIM * DIM, b1 + l * DIM, outb, N);
        // h = hidden @ w2 + b2
        gemm_kernel<1, false><<<GB, 256, 0, stream>>>(
            outb, nullptr, nullptr, nullptr,
            w2 + (size_t)l * DIM * DIM, b2 + l * DIM, hbuf[l], N);
    }
    gemm_kernel<4, false><<<GB, 256, 0, stream>>>(
        x, hbuf[0], hbuf[1], hbuf[2], fw, fb, out, N);
}